// Round 3
// baseline (519.302 us; speedup 1.0000x reference)
//
#include <hip/hip_runtime.h>
#include <math.h>

#define NBATCH 2
#define CHN    64
#define NYY    80
#define NXX    80
#define NCLS   80
#define NPIX   6400      // 80*80
#define KTOT   512000    // NCLS*NPIX
#define NOUT   85        // 5 + NCLS
#define NBLK   500       // KTOT / 1024

// ---------------- K1a: hm 3x3 conv (pad 1) + ReLU, FP64 ----------------
// grid (25, 64, 2): x = pixel chunk, y = out channel, z = batch
__global__ void conv1_hm_kernel(const float* __restrict__ x,
                                const float* __restrict__ w1,
                                const float* __restrict__ b1,
                                double* __restrict__ c1)
{
    int p  = blockIdx.x * 256 + threadIdx.x;
    int oc = blockIdx.y;
    int b  = blockIdx.z;

    int y  = p / NXX;
    int xx = p % NXX;
    const float* xin = x + (size_t)b * CHN * NPIX;
    const float* wo  = w1 + (size_t)oc * CHN * 9;

    double acc = (double)b1[oc];
    bool xm = (xx > 0), xp = (xx < NXX - 1);

    #pragma unroll
    for (int ky = 0; ky < 3; ky++) {
        int yy = y + ky - 1;
        if ((unsigned)yy >= (unsigned)NYY) continue;
        const float* xb = xin + yy * NXX;
        const float* wk = wo + ky * 3;
        for (int ic = 0; ic < CHN; ic++) {
            const float* xr = xb + (size_t)ic * NPIX;
            const float* wr = wk + ic * 9;
            double w0 = (double)wr[0], w1v = (double)wr[1], w2 = (double)wr[2];
            if (xm) acc += (double)xr[xx - 1] * w0;
            acc += (double)xr[xx] * w1v;
            if (xp) acc += (double)xr[xx + 1] * w2;
        }
    }
    acc = acc > 0.0 ? acc : 0.0;
    c1[((size_t)b * CHN + oc) * NPIX + p] = acc;
}

// ---------------- K1b: wh/reg 3x3 conv (pad 1) + ReLU, FP32 ----------------
// grid (25, 64, 4): z = head*2 + b  (head 0 = wh, 1 = reg)
__global__ void conv1_wr_kernel(const float* __restrict__ x,
                                const float* __restrict__ ww1, const float* __restrict__ wb1,
                                const float* __restrict__ rw1, const float* __restrict__ rb1,
                                float* __restrict__ c1)
{
    int p   = blockIdx.x * 256 + threadIdx.x;
    int oc  = blockIdx.y;
    int hz  = blockIdx.z;
    int head = hz >> 1, b = hz & 1;

    const float* w1 = (head == 0) ? ww1 : rw1;
    const float* b1 = (head == 0) ? wb1 : rb1;

    int y  = p / NXX;
    int xx = p % NXX;
    const float* xin = x + (size_t)b * CHN * NPIX;
    const float* wo  = w1 + (size_t)oc * CHN * 9;

    float acc = b1[oc];
    bool xm = (xx > 0), xp = (xx < NXX - 1);

    #pragma unroll
    for (int ky = 0; ky < 3; ky++) {
        int yy = y + ky - 1;
        if ((unsigned)yy >= (unsigned)NYY) continue;
        const float* xb = xin + yy * NXX;
        const float* wk = wo + ky * 3;
        for (int ic = 0; ic < CHN; ic++) {
            const float* xr = xb + (size_t)ic * NPIX;
            const float* wr = wk + ic * 9;
            float w0 = wr[0], w1v = wr[1], w2 = wr[2];
            if (xm) acc += xr[xx - 1] * w0;
            acc += xr[xx] * w1v;
            if (xp) acc += xr[xx + 1] * w2;
        }
    }
    acc = fmaxf(acc, 0.f);
    c1[((size_t)hz * CHN + oc) * NPIX + p] = acc;
}

// ---------------- K2a: hm 1x1 conv + sigmoid, FP64 ----------------
// grid (25, 80, 2)
__global__ void conv2_hm_kernel(const double* __restrict__ c1,
                                const float* __restrict__ w2,
                                const float* __restrict__ b2,
                                double* __restrict__ hm_s)
{
    int p  = blockIdx.x * 256 + threadIdx.x;
    int oc = blockIdx.y;
    int b  = blockIdx.z;

    const double* in = c1 + (size_t)b * CHN * NPIX;
    const float*  w  = w2 + (size_t)oc * CHN;
    double acc = (double)b2[oc];
    for (int ic = 0; ic < CHN; ic++)
        acc += in[(size_t)ic * NPIX + p] * (double)w[ic];
    hm_s[((size_t)b * NCLS + oc) * NPIX + p] = 1.0 / (1.0 + exp(-acc));
}

// ---------------- K2b: wh/reg 1x1 conv + relu, FP32 ----------------
// grid (25, 4, 2): y = head*2 + ch
__global__ void conv2_wr_kernel(const float* __restrict__ c1,
                                const float* __restrict__ wh_w2, const float* __restrict__ wh_b2,
                                const float* __restrict__ rg_w2, const float* __restrict__ rg_b2,
                                float* __restrict__ wh, float* __restrict__ rg)
{
    int p  = blockIdx.x * 256 + threadIdx.x;
    int hc = blockIdx.y;            // head*2 + ch
    int b  = blockIdx.z;
    int head = hc >> 1, ch = hc & 1;

    const float* in = c1 + ((size_t)(head * 2 + b) * CHN) * NPIX;
    const float* w  = (head == 0) ? wh_w2 + (size_t)ch * CHN : rg_w2 + (size_t)ch * CHN;
    float bias      = (head == 0) ? wh_b2[ch] : rg_b2[ch];

    float acc = bias;
    for (int ic = 0; ic < CHN; ic++) acc += in[(size_t)ic * NPIX + p] * w[ic];
    acc = fmaxf(acc, 0.f);
    float* o = (head == 0) ? wh : rg;
    o[((size_t)b * 2 + ch) * NPIX + p] = acc;
}

// ---------------- K3a: maxima flags (fp64 compare) + per-block counts ----------------
// grid (500, 2), block 1024. k = c*6400 + y*80 + x (scan order).
__global__ void flags_kernel(const double* __restrict__ hm_s,
                             unsigned long long* __restrict__ ballots,
                             unsigned int* __restrict__ counts)
{
    int b = blockIdx.y;
    int k = blockIdx.x * 1024 + threadIdx.x;
    int c = k / NPIX;
    int p = k - c * NPIX;
    int y = p / NXX, xx = p - y * NXX;

    const double* h = hm_s + ((size_t)b * NCLS + c) * NPIX;
    double s = h[p];
    double m = s;
    #pragma unroll
    for (int dy = -1; dy <= 1; dy++) {
        int yy = y + dy;
        if ((unsigned)yy >= (unsigned)NYY) continue;
        const double* hr = h + yy * NXX;
        #pragma unroll
        for (int dx = -1; dx <= 1; dx++) {
            int xn = xx + dx;
            if ((unsigned)xn >= (unsigned)NXX) continue;
            double v = hr[xn];
            m = v > m ? v : m;
        }
    }
    bool flag = (s == m);
    unsigned long long ball = __ballot(flag);
    int lane = threadIdx.x & 63;
    int wave = threadIdx.x >> 6;

    __shared__ unsigned int wcnt[16];
    if (lane == 0) {
        ballots[(size_t)b * 8000 + blockIdx.x * 16 + wave] = ball;
        wcnt[wave] = __popcll(ball);
    }
    __syncthreads();
    if (threadIdx.x == 0) {
        unsigned int t = 0;
        for (int i = 0; i < 16; i++) t += wcnt[i];
        counts[b * NBLK + blockIdx.x] = t;
    }
}

// ---------------- K3b: exclusive scan of 500 block counts per batch ----------------
__global__ void scan_kernel(const unsigned int* __restrict__ counts,
                            unsigned int* __restrict__ offs)
{
    int b = blockIdx.x;
    int t = threadIdx.x;
    unsigned int v = (t < NBLK) ? counts[b * NBLK + t] : 0u;
    unsigned int xi = v;
    #pragma unroll
    for (int d = 1; d < 64; d <<= 1) {
        unsigned int n = __shfl_up(xi, d, 64);
        if ((t & 63) >= d) xi += n;
    }
    __shared__ unsigned int wtot[8];
    __shared__ unsigned int wbase[8];
    if ((t & 63) == 63) wtot[t >> 6] = xi;
    __syncthreads();
    if (t == 0) {
        unsigned int a = 0;
        for (int i = 0; i < 8; i++) { wbase[i] = a; a += wtot[i]; }
    }
    __syncthreads();
    unsigned int excl = xi - v + wbase[t >> 6];
    if (t < NBLK) offs[b * NBLK + t] = excl;
}

// ---------------- K3c: scatter maxima rows (fp32 output) ----------------
__global__ void scatter_kernel(const unsigned long long* __restrict__ ballots,
                               const unsigned int* __restrict__ offs,
                               const double* __restrict__ hm_s,
                               const float* __restrict__ wh,
                               const float* __restrict__ rg,
                               const float* __restrict__ offsets,
                               float* __restrict__ out)
{
    int b = blockIdx.y;
    int k = blockIdx.x * 1024 + threadIdx.x;
    int lane = threadIdx.x & 63;
    int wave = threadIdx.x >> 6;

    unsigned long long ball = ballots[(size_t)b * 8000 + blockIdx.x * 16 + wave];

    __shared__ unsigned int wc[16];
    __shared__ unsigned int wb[16];
    if (lane == 0) wc[wave] = __popcll(ball);
    __syncthreads();
    if (threadIdx.x == 0) {
        unsigned int a = 0;
        for (int i = 0; i < 16; i++) { wb[i] = a; a += wc[i]; }
    }
    __syncthreads();

    bool flag = (ball >> lane) & 1ull;
    if (!flag) return;

    unsigned int rank = offs[b * NBLK + blockIdx.x] + wb[wave]
                      + (unsigned int)__popcll(ball & ((1ull << lane) - 1ull));

    int c = k / NPIX;
    int p = k - c * NPIX;
    int y = p / NXX, xx = p - y * NXX;

    float offx = offsets[b * 3 + 1];
    float offy = offsets[b * 3 + 2];
    float r0 = rg[((size_t)b * 2 + 0) * NPIX + p];
    float r1 = rg[((size_t)b * 2 + 1) * NPIX + p];
    float w0 = wh[((size_t)b * 2 + 0) * NPIX + p];
    float w1 = wh[((size_t)b * 2 + 1) * NPIX + p];
    float s  = (float)hm_s[((size_t)b * NCLS + c) * NPIX + p];

    float cx = ((float)xx + 2.f * offx + r0) * 4.f;
    float cy = ((float)y  + 2.f * offy + r1) * 4.f;

    float* row = out + ((size_t)b * KTOT + rank) * NOUT;
    row[0] = cx;
    row[1] = cy;
    row[2] = w0 * 4.f;
    row[3] = w1 * 4.f;
    row[4] = s;
    row[5 + c] = 1.f;
}

extern "C" void kernel_launch(void* const* d_in, const int* in_sizes, int n_in,
                              void* d_out, int out_size, void* d_ws, size_t ws_size,
                              hipStream_t stream)
{
    const float* x       = (const float*)d_in[0];
    const float* offsets = (const float*)d_in[1];
    const float* hm_w1   = (const float*)d_in[2];
    const float* hm_b1   = (const float*)d_in[3];
    const float* hm_w2   = (const float*)d_in[4];
    const float* hm_b2   = (const float*)d_in[5];
    const float* wh_w1   = (const float*)d_in[6];
    const float* wh_b1   = (const float*)d_in[7];
    const float* wh_w2   = (const float*)d_in[8];
    const float* wh_b2   = (const float*)d_in[9];
    const float* reg_w1  = (const float*)d_in[10];
    const float* reg_b1  = (const float*)d_in[11];
    const float* reg_w2  = (const float*)d_in[12];
    const float* reg_b2  = (const float*)d_in[13];

    float* out = (float*)d_out;

    // workspace layout
    char* wp = (char*)d_ws;
    double* c1hm = (double*)wp;                 wp += (size_t)NBATCH * CHN * NPIX * 8;       // 6.55 MB
    double* hm_s = (double*)wp;                 wp += (size_t)NBATCH * NCLS * NPIX * 8;      // 8.19 MB
    float*  c1wr = (float*)wp;                  wp += (size_t)2 * NBATCH * CHN * NPIX * 4;   // 6.55 MB
    float*  wh   = (float*)wp;                  wp += (size_t)NBATCH * 2 * NPIX * 4;
    float*  rg   = (float*)wp;                  wp += (size_t)NBATCH * 2 * NPIX * 4;
    unsigned long long* ballots = (unsigned long long*)wp; wp += (size_t)NBATCH * 8000 * 8;
    unsigned int* counts = (unsigned int*)wp;   wp += (size_t)NBATCH * NBLK * 4;
    unsigned int* offs   = (unsigned int*)wp;

    hipMemsetAsync(d_out, 0, (size_t)out_size * sizeof(float), stream);

    conv1_hm_kernel<<<dim3(25, 64, 2), 256, 0, stream>>>(x, hm_w1, hm_b1, c1hm);

    conv1_wr_kernel<<<dim3(25, 64, 4), 256, 0, stream>>>(
        x, wh_w1, wh_b1, reg_w1, reg_b1, c1wr);

    conv2_hm_kernel<<<dim3(25, 80, 2), 256, 0, stream>>>(c1hm, hm_w2, hm_b2, hm_s);

    conv2_wr_kernel<<<dim3(25, 4, 2), 256, 0, stream>>>(
        c1wr, wh_w2, wh_b2, reg_w2, reg_b2, wh, rg);

    flags_kernel<<<dim3(NBLK, 2), 1024, 0, stream>>>(hm_s, ballots, counts);

    scan_kernel<<<2, 512, 0, stream>>>(counts, offs);

    scatter_kernel<<<dim3(NBLK, 2), 1024, 0, stream>>>(
        ballots, offs, hm_s, wh, rg, offsets, out);
}

// Round 4
// 207.534 us; speedup vs baseline: 2.5023x; 2.5023x over previous
//
#include <hip/hip_runtime.h>
#include <math.h>

#define NBATCH 2
#define CHN    64
#define NYY    80
#define NXX    80
#define NCLS   80
#define NPIX   6400      // 80*80
#define KTOT   512000    // NCLS*NPIX
#define NOUT   85        // 5 + NCLS
#define NBLK   500       // KTOT / 1024

// ============ K1: unified 3x3 conv+ReLU, LDS-tiled ============
// grid (20, 2, 6): x = ytile (4 rows), y = ocg (32 oc), z = img
// img 0,1 = hm b0,b1 (fp64 acc); 2,3 = wh b0,b1; 4,5 = reg b0,b1 (fp32)
// block 640 = 80 px-groups(4px) x 8 oc-groups(4oc)
__global__ __launch_bounds__(640)
void conv1_all_kernel(const float* __restrict__ x,
                      const float* __restrict__ hw1, const float* __restrict__ hb1,
                      const float* __restrict__ ww1, const float* __restrict__ wb1,
                      const float* __restrict__ rw1, const float* __restrict__ rb1,
                      double* __restrict__ c1hm, float* __restrict__ c1wr)
{
    __shared__ float lx[16][6][80];    // 30.7 KB
    __shared__ float lw[144][32];      // 18.4 KB  [ic*9+tap][oc_local]

    const int ytile = blockIdx.x;
    const int ocg   = blockIdx.y;
    const int img   = blockIdx.z;
    const int t     = threadIdx.x;

    const int b    = (img < 2) ? img : (img & 1);
    const int head = (img < 2) ? 0 : ((img < 4) ? 1 : 2);
    const float* w1 = (head == 0) ? hw1 : ((head == 1) ? ww1 : rw1);
    const float* b1 = (head == 0) ? hb1 : ((head == 1) ? wb1 : rb1);
    const float* xin = x + (size_t)b * CHN * NPIX;

    const int pxq = t % 80;            // 4-px group
    const int ocq = t / 80;            // 0..7
    const int r   = pxq / 20;          // tile row 0..3
    const int c   = (pxq % 20) * 4;    // col 0..76
    const int oc0 = ocg * 32 + ocq * 4;
    const int gy0 = ytile * 4;

#define STAGE(ICC)                                                              \
    do {                                                                        \
        for (int j = t; j < 1920; j += 640) {                                   \
            int ic_l = j / 120; int rem = j % 120;                              \
            int row_l = rem / 20; int c4 = rem % 20;                            \
            int gy = gy0 - 1 + row_l;                                           \
            float4 v = make_float4(0.f, 0.f, 0.f, 0.f);                         \
            if ((unsigned)gy < 80u)                                             \
                v = *(const float4*)(xin + (size_t)((ICC) + ic_l) * NPIX        \
                                     + gy * NXX + c4 * 4);                      \
            *(float4*)&lx[ic_l][row_l][c4 * 4] = v;                             \
        }                                                                       \
        for (int j = t; j < 4608; j += 640) {                                   \
            int oc_l = j % 32; int k = j / 32; /* k = ic*9+tap, 0..143 */       \
            int ic_l = k / 9;  int tap = k % 9;                                 \
            lw[k][oc_l] = w1[((size_t)(ocg * 32 + oc_l) * CHN + (ICC) + ic_l)   \
                             * 9 + tap];                                        \
        }                                                                       \
    } while (0)

    if (img < 2) {
        // ---------------- fp64 accumulation (hm head) ----------------
        double acc[4][4];
        #pragma unroll
        for (int j = 0; j < 4; j++)
            #pragma unroll
            for (int o = 0; o < 4; o++) acc[j][o] = (double)b1[oc0 + o];

        for (int icc = 0; icc < CHN; icc += 16) {
            __syncthreads();
            STAGE(icc);
            __syncthreads();
            for (int ic = 0; ic < 16; ic++) {
                double xw[3][6];
                #pragma unroll
                for (int ky = 0; ky < 3; ky++) {
                    const float* row = &lx[ic][r + ky][0];
                    xw[ky][0] = (c > 0) ? (double)row[c - 1] : 0.0;
                    float4 m = *(const float4*)&row[c];
                    xw[ky][1] = (double)m.x; xw[ky][2] = (double)m.y;
                    xw[ky][3] = (double)m.z; xw[ky][4] = (double)m.w;
                    xw[ky][5] = (c < 76) ? (double)row[c + 4] : 0.0;
                }
                #pragma unroll
                for (int ky = 0; ky < 3; ky++)
                #pragma unroll
                for (int kx = 0; kx < 3; kx++) {
                    float4 wv = *(const float4*)&lw[ic * 9 + ky * 3 + kx][ocq * 4];
                    double w0 = (double)wv.x, w1d = (double)wv.y,
                           w2 = (double)wv.z, w3 = (double)wv.w;
                    #pragma unroll
                    for (int j = 0; j < 4; j++) {
                        double xv = xw[ky][j + kx];
                        acc[j][0] += xv * w0; acc[j][1] += xv * w1d;
                        acc[j][2] += xv * w2; acc[j][3] += xv * w3;
                    }
                }
            }
        }
        size_t pix = (size_t)(gy0 + r) * NXX + c;
        #pragma unroll
        for (int o = 0; o < 4; o++) {
            double* dst = c1hm + ((size_t)b * CHN + oc0 + o) * NPIX + pix;
            double2 lo, hi;
            lo.x = acc[0][o] > 0.0 ? acc[0][o] : 0.0;
            lo.y = acc[1][o] > 0.0 ? acc[1][o] : 0.0;
            hi.x = acc[2][o] > 0.0 ? acc[2][o] : 0.0;
            hi.y = acc[3][o] > 0.0 ? acc[3][o] : 0.0;
            *(double2*)dst = lo;
            *(double2*)(dst + 2) = hi;
        }
    } else {
        // ---------------- fp32 accumulation (wh/reg heads) ----------------
        float acc[4][4];
        #pragma unroll
        for (int j = 0; j < 4; j++)
            #pragma unroll
            for (int o = 0; o < 4; o++) acc[j][o] = b1[oc0 + o];

        for (int icc = 0; icc < CHN; icc += 16) {
            __syncthreads();
            STAGE(icc);
            __syncthreads();
            for (int ic = 0; ic < 16; ic++) {
                float xw[3][6];
                #pragma unroll
                for (int ky = 0; ky < 3; ky++) {
                    const float* row = &lx[ic][r + ky][0];
                    xw[ky][0] = (c > 0) ? row[c - 1] : 0.f;
                    float4 m = *(const float4*)&row[c];
                    xw[ky][1] = m.x; xw[ky][2] = m.y;
                    xw[ky][3] = m.z; xw[ky][4] = m.w;
                    xw[ky][5] = (c < 76) ? row[c + 4] : 0.f;
                }
                #pragma unroll
                for (int ky = 0; ky < 3; ky++)
                #pragma unroll
                for (int kx = 0; kx < 3; kx++) {
                    float4 wv = *(const float4*)&lw[ic * 9 + ky * 3 + kx][ocq * 4];
                    #pragma unroll
                    for (int j = 0; j < 4; j++) {
                        float xv = xw[ky][j + kx];
                        acc[j][0] += xv * wv.x; acc[j][1] += xv * wv.y;
                        acc[j][2] += xv * wv.z; acc[j][3] += xv * wv.w;
                    }
                }
            }
        }
        int hz = img - 2;  // 0=wh b0, 1=wh b1, 2=reg b0, 3=reg b1
        size_t pix = (size_t)(gy0 + r) * NXX + c;
        #pragma unroll
        for (int o = 0; o < 4; o++) {
            float4 v;
            v.x = fmaxf(acc[0][o], 0.f); v.y = fmaxf(acc[1][o], 0.f);
            v.z = fmaxf(acc[2][o], 0.f); v.w = fmaxf(acc[3][o], 0.f);
            *(float4*)(c1wr + ((size_t)hz * CHN + oc0 + o) * NPIX + pix) = v;
        }
    }
#undef STAGE
}

// ============ K2a: hm 1x1 conv + sigmoid, FP64, 4 oc/thread ============
// grid (25, 20, 2)
__global__ void conv2_hm_kernel(const double* __restrict__ c1,
                                const float* __restrict__ w2,
                                const float* __restrict__ b2,
                                double* __restrict__ hm_s)
{
    int p   = blockIdx.x * 256 + threadIdx.x;
    int oc0 = blockIdx.y * 4;
    int b   = blockIdx.z;

    const double* in = c1 + (size_t)b * CHN * NPIX;
    double acc[4];
    #pragma unroll
    for (int o = 0; o < 4; o++) acc[o] = (double)b2[oc0 + o];

    for (int ic = 0; ic < CHN; ic++) {
        double xv = in[(size_t)ic * NPIX + p];
        #pragma unroll
        for (int o = 0; o < 4; o++)
            acc[o] += xv * (double)w2[(size_t)(oc0 + o) * CHN + ic];
    }
    #pragma unroll
    for (int o = 0; o < 4; o++)
        hm_s[((size_t)b * NCLS + oc0 + o) * NPIX + p] = 1.0 / (1.0 + exp(-acc[o]));
}

// ============ K2b: wh/reg 1x1 conv + relu, FP32 ============
// grid (25, 4, 2): y = head*2 + ch
__global__ void conv2_wr_kernel(const float* __restrict__ c1,
                                const float* __restrict__ wh_w2, const float* __restrict__ wh_b2,
                                const float* __restrict__ rg_w2, const float* __restrict__ rg_b2,
                                float* __restrict__ wh, float* __restrict__ rg)
{
    int p  = blockIdx.x * 256 + threadIdx.x;
    int hc = blockIdx.y;
    int b  = blockIdx.z;
    int head = hc >> 1, ch = hc & 1;

    const float* in = c1 + ((size_t)(head * 2 + b) * CHN) * NPIX;
    const float* w  = (head == 0) ? wh_w2 + (size_t)ch * CHN : rg_w2 + (size_t)ch * CHN;
    float bias      = (head == 0) ? wh_b2[ch] : rg_b2[ch];

    float acc = bias;
    for (int ic = 0; ic < CHN; ic++) acc += in[(size_t)ic * NPIX + p] * w[ic];
    acc = fmaxf(acc, 0.f);
    float* o = (head == 0) ? wh : rg;
    o[((size_t)b * 2 + ch) * NPIX + p] = acc;
}

// ============ K3a: maxima flags (fp64 compare) + per-block counts ============
__global__ void flags_kernel(const double* __restrict__ hm_s,
                             unsigned long long* __restrict__ ballots,
                             unsigned int* __restrict__ counts)
{
    int b = blockIdx.y;
    int k = blockIdx.x * 1024 + threadIdx.x;
    int c = k / NPIX;
    int p = k - c * NPIX;
    int y = p / NXX, xx = p - y * NXX;

    const double* h = hm_s + ((size_t)b * NCLS + c) * NPIX;
    double s = h[p];
    double m = s;
    #pragma unroll
    for (int dy = -1; dy <= 1; dy++) {
        int yy = y + dy;
        if ((unsigned)yy >= (unsigned)NYY) continue;
        const double* hr = h + yy * NXX;
        #pragma unroll
        for (int dx = -1; dx <= 1; dx++) {
            int xn = xx + dx;
            if ((unsigned)xn >= (unsigned)NXX) continue;
            double v = hr[xn];
            m = v > m ? v : m;
        }
    }
    bool flag = (s == m);
    unsigned long long ball = __ballot(flag);
    int lane = threadIdx.x & 63;
    int wave = threadIdx.x >> 6;

    __shared__ unsigned int wcnt[16];
    if (lane == 0) {
        ballots[(size_t)b * 8000 + blockIdx.x * 16 + wave] = ball;
        wcnt[wave] = __popcll(ball);
    }
    __syncthreads();
    if (threadIdx.x == 0) {
        unsigned int tot = 0;
        for (int i = 0; i < 16; i++) tot += wcnt[i];
        counts[b * NBLK + blockIdx.x] = tot;
    }
}

// ============ K3b: exclusive scan of 500 block counts per batch ============
__global__ void scan_kernel(const unsigned int* __restrict__ counts,
                            unsigned int* __restrict__ offs)
{
    int b = blockIdx.x;
    int t = threadIdx.x;
    unsigned int v = (t < NBLK) ? counts[b * NBLK + t] : 0u;
    unsigned int xi = v;
    #pragma unroll
    for (int d = 1; d < 64; d <<= 1) {
        unsigned int n = __shfl_up(xi, d, 64);
        if ((t & 63) >= d) xi += n;
    }
    __shared__ unsigned int wtot[8];
    __shared__ unsigned int wbase[8];
    if ((t & 63) == 63) wtot[t >> 6] = xi;
    __syncthreads();
    if (t == 0) {
        unsigned int a = 0;
        for (int i = 0; i < 8; i++) { wbase[i] = a; a += wtot[i]; }
    }
    __syncthreads();
    unsigned int excl = xi - v + wbase[t >> 6];
    if (t < NBLK) offs[b * NBLK + t] = excl;
}

// ============ K3c: scatter maxima rows (fp32 output) ============
__global__ void scatter_kernel(const unsigned long long* __restrict__ ballots,
                               const unsigned int* __restrict__ offs,
                               const double* __restrict__ hm_s,
                               const float* __restrict__ wh,
                               const float* __restrict__ rg,
                               const float* __restrict__ offsets,
                               float* __restrict__ out)
{
    int b = blockIdx.y;
    int k = blockIdx.x * 1024 + threadIdx.x;
    int lane = threadIdx.x & 63;
    int wave = threadIdx.x >> 6;

    unsigned long long ball = ballots[(size_t)b * 8000 + blockIdx.x * 16 + wave];

    __shared__ unsigned int wc[16];
    __shared__ unsigned int wb[16];
    if (lane == 0) wc[wave] = __popcll(ball);
    __syncthreads();
    if (threadIdx.x == 0) {
        unsigned int a = 0;
        for (int i = 0; i < 16; i++) { wb[i] = a; a += wc[i]; }
    }
    __syncthreads();

    bool flag = (ball >> lane) & 1ull;
    if (!flag) return;

    unsigned int rank = offs[b * NBLK + blockIdx.x] + wb[wave]
                      + (unsigned int)__popcll(ball & ((1ull << lane) - 1ull));

    int c = k / NPIX;
    int p = k - c * NPIX;
    int y = p / NXX, xx = p - y * NXX;

    float offx = offsets[b * 3 + 1];
    float offy = offsets[b * 3 + 2];
    float r0 = rg[((size_t)b * 2 + 0) * NPIX + p];
    float r1 = rg[((size_t)b * 2 + 1) * NPIX + p];
    float w0 = wh[((size_t)b * 2 + 0) * NPIX + p];
    float w1 = wh[((size_t)b * 2 + 1) * NPIX + p];
    float s  = (float)hm_s[((size_t)b * NCLS + c) * NPIX + p];

    float cx = ((float)xx + 2.f * offx + r0) * 4.f;
    float cy = ((float)y  + 2.f * offy + r1) * 4.f;

    float* row = out + ((size_t)b * KTOT + rank) * NOUT;
    row[0] = cx;
    row[1] = cy;
    row[2] = w0 * 4.f;
    row[3] = w1 * 4.f;
    row[4] = s;
    row[5 + c] = 1.f;
}

extern "C" void kernel_launch(void* const* d_in, const int* in_sizes, int n_in,
                              void* d_out, int out_size, void* d_ws, size_t ws_size,
                              hipStream_t stream)
{
    const float* x       = (const float*)d_in[0];
    const float* offsets = (const float*)d_in[1];
    const float* hm_w1   = (const float*)d_in[2];
    const float* hm_b1   = (const float*)d_in[3];
    const float* hm_w2   = (const float*)d_in[4];
    const float* hm_b2   = (const float*)d_in[5];
    const float* wh_w1   = (const float*)d_in[6];
    const float* wh_b1   = (const float*)d_in[7];
    const float* wh_w2   = (const float*)d_in[8];
    const float* wh_b2   = (const float*)d_in[9];
    const float* reg_w1  = (const float*)d_in[10];
    const float* reg_b1  = (const float*)d_in[11];
    const float* reg_w2  = (const float*)d_in[12];
    const float* reg_b2  = (const float*)d_in[13];

    float* out = (float*)d_out;

    // workspace layout (same as round 3)
    char* wp = (char*)d_ws;
    double* c1hm = (double*)wp;                 wp += (size_t)NBATCH * CHN * NPIX * 8;
    double* hm_s = (double*)wp;                 wp += (size_t)NBATCH * NCLS * NPIX * 8;
    float*  c1wr = (float*)wp;                  wp += (size_t)2 * NBATCH * CHN * NPIX * 4;
    float*  wh   = (float*)wp;                  wp += (size_t)NBATCH * 2 * NPIX * 4;
    float*  rg   = (float*)wp;                  wp += (size_t)NBATCH * 2 * NPIX * 4;
    unsigned long long* ballots = (unsigned long long*)wp; wp += (size_t)NBATCH * 8000 * 8;
    unsigned int* counts = (unsigned int*)wp;   wp += (size_t)NBATCH * NBLK * 4;
    unsigned int* offs   = (unsigned int*)wp;

    hipMemsetAsync(d_out, 0, (size_t)out_size * sizeof(float), stream);

    conv1_all_kernel<<<dim3(20, 2, 6), 640, 0, stream>>>(
        x, hm_w1, hm_b1, wh_w1, wh_b1, reg_w1, reg_b1, c1hm, c1wr);

    conv2_hm_kernel<<<dim3(25, 20, 2), 256, 0, stream>>>(c1hm, hm_w2, hm_b2, hm_s);

    conv2_wr_kernel<<<dim3(25, 4, 2), 256, 0, stream>>>(
        c1wr, wh_w2, wh_b2, reg_w2, reg_b2, wh, rg);

    flags_kernel<<<dim3(NBLK, 2), 1024, 0, stream>>>(hm_s, ballots, counts);

    scan_kernel<<<2, 512, 0, stream>>>(counts, offs);

    scatter_kernel<<<dim3(NBLK, 2), 1024, 0, stream>>>(
        ballots, offs, hm_s, wh, rg, offsets, out);
}

// Round 6
// 197.587 us; speedup vs baseline: 2.6282x; 1.0503x over previous
//
#include <hip/hip_runtime.h>
#include <math.h>

#define NBATCH 2
#define CHN    64
#define NYY    80
#define NXX    80
#define NCLS   80
#define NPIX   6400      // 80*80
#define KTOT   512000    // NCLS*NPIX
#define NOUT   85        // 5 + NCLS
#define NBLK   500       // KTOT / 1024

typedef float vf4 __attribute__((ext_vector_type(4)));

// output = 2*512000*85 floats = 87,040,000 = 21,760,000 float4 quads
#define QTOT   21760000L
// zero-fill slice boundaries (in quads)
#define QHM0   0L
#define QHM1   4352000L      // conv1_hm: 20%
#define QWR1   14144000L     // conv1_wr: 45%
#define QFL1   19584000L     // flags:    25%
#define QC21   21760000L     // conv2_hm: 10%

// ============ K1a: hm 3x3 conv + ReLU, FP64, balanced tiles ============
// grid (40, 4, 2): x = ytile (2 rows), y = ocg (16 oc), z = batch; 320 thr
__global__ __launch_bounds__(320)
void conv1_hm_kernel(const float* __restrict__ x,
                     const float* __restrict__ w1,
                     const float* __restrict__ b1,
                     double* __restrict__ c1,
                     vf4* __restrict__ outq)
{
    __shared__ double lx[16][4][82];   // halo col 0 and 81 are zero pads; 42.0 KB
    __shared__ double lw[144][16];     // [ic*9+tap][oc_local]; 18.4 KB

    const int yt  = blockIdx.x;
    const int ocg = blockIdx.y;
    const int b   = blockIdx.z;
    const int t   = threadIdx.x;

    const int pxq = t % 80;            // 2-px group
    const int ocq = t / 80;            // 0..3
    const int r   = pxq / 40;          // tile row 0..1
    const int c   = (pxq % 40) * 2;    // col 0..78 (even)
    const int oc0 = ocg * 16 + ocq * 4;
    const int gy0 = yt * 2;

    const float* xin = x + (size_t)b * CHN * NPIX;

    const int bl   = (blockIdx.z * 4 + blockIdx.y) * 40 + blockIdx.x;
    const int gtid = bl * 320 + t;
    const int nth  = 320 * 320;        // 102400
    const vf4 fz = {0.f, 0.f, 0.f, 0.f};

    double acc[2][4];
    #pragma unroll
    for (int j = 0; j < 2; j++)
        #pragma unroll
        for (int o = 0; o < 4; o++) acc[j][o] = (double)b1[oc0 + o];

    for (int cc = 0; cc < 4; cc++) {
        const int icc = cc * 16;
        __syncthreads();
        // stage x tile as double, with halo cols zeroed
        for (int j = t; j < 1280; j += 320) {
            int ic_l = j / 80; int rem = j % 80;
            int row_l = rem / 20; int c4 = (rem % 20) * 4;
            int gy = gy0 - 1 + row_l;
            float4 v = make_float4(0.f, 0.f, 0.f, 0.f);
            if ((unsigned)gy < 80u)
                v = *(const float4*)(xin + (size_t)(icc + ic_l) * NPIX + gy * NXX + c4);
            lx[ic_l][row_l][c4 + 1] = (double)v.x;
            lx[ic_l][row_l][c4 + 2] = (double)v.y;
            lx[ic_l][row_l][c4 + 3] = (double)v.z;
            lx[ic_l][row_l][c4 + 4] = (double)v.w;
        }
        for (int j = t; j < 64; j += 320) {     // 16 ic * 4 rows halo pads
            lx[j / 4][j % 4][0]  = 0.0;
            lx[j / 4][j % 4][81] = 0.0;
        }
        // stage weights as double
        for (int j = t; j < 2304; j += 320) {
            int oc_l = j % 16; int k = j / 16;  // k = ic*9+tap
            int ic_l = k / 9, tap = k % 9;
            lw[k][oc_l] = (double)w1[((size_t)(ocg * 16 + oc_l) * CHN + icc + ic_l) * 9 + tap];
        }
        __syncthreads();
        // zero-fill slice, phase cc (stores drain under the fp64 compute)
        {
            int i0 = cc * 11, i1 = (cc == 3) ? 43 : (cc * 11 + 11);
            for (int i = i0; i < i1; i++) {
                long q = QHM0 + (long)gtid + (long)i * nth;
                if (q < QHM1) __builtin_nontemporal_store(fz, outq + q);
            }
        }
        for (int ic = 0; ic < 16; ic++) {
            double xw[3][4];                    // cols c-1..c+2 (halo layout: lx[.][.][c..c+3])
            #pragma unroll
            for (int ky = 0; ky < 3; ky++) {
                const double* row = &lx[ic][r + ky][0];
                double2 a = *(const double2*)&row[c];
                double2 bb = *(const double2*)&row[c + 2];
                xw[ky][0] = a.x; xw[ky][1] = a.y; xw[ky][2] = bb.x; xw[ky][3] = bb.y;
            }
            #pragma unroll
            for (int ky = 0; ky < 3; ky++)
            #pragma unroll
            for (int kx = 0; kx < 3; kx++) {
                const double* wv = &lw[ic * 9 + ky * 3 + kx][ocq * 4];
                double w0 = wv[0], w1d = wv[1], w2 = wv[2], w3 = wv[3];
                double x0 = xw[ky][kx], x1 = xw[ky][kx + 1];
                acc[0][0] += x0 * w0; acc[0][1] += x0 * w1d;
                acc[0][2] += x0 * w2; acc[0][3] += x0 * w3;
                acc[1][0] += x1 * w0; acc[1][1] += x1 * w1d;
                acc[1][2] += x1 * w2; acc[1][3] += x1 * w3;
            }
        }
    }
    size_t pix = (size_t)(gy0 + r) * NXX + c;
    #pragma unroll
    for (int o = 0; o < 4; o++) {
        double2 v;
        v.x = acc[0][o] > 0.0 ? acc[0][o] : 0.0;
        v.y = acc[1][o] > 0.0 ? acc[1][o] : 0.0;
        *(double2*)(c1 + ((size_t)b * CHN + oc0 + o) * NPIX + pix) = v;
    }
}

// ============ K1b: wh/reg 3x3 conv + ReLU, FP32, balanced tiles ============
// grid (20, 4, 4): x = ytile (4 rows), y = ocg (16 oc), z = img; 320 thr
// img: 0=wh b0, 1=wh b1, 2=reg b0, 3=reg b1
__global__ __launch_bounds__(320)
void conv1_wr_kernel(const float* __restrict__ x,
                     const float* __restrict__ ww1, const float* __restrict__ wb1,
                     const float* __restrict__ rw1, const float* __restrict__ rb1,
                     float* __restrict__ c1,
                     vf4* __restrict__ outq)
{
    __shared__ float lx[16][6][80];    // 30.7 KB
    __shared__ float lw[144][16];      // 9.2 KB

    const int yt  = blockIdx.x;
    const int ocg = blockIdx.y;
    const int img = blockIdx.z;
    const int t   = threadIdx.x;

    const int head = img >> 1, b = img & 1;
    const float* w1 = (head == 0) ? ww1 : rw1;
    const float* b1 = (head == 0) ? wb1 : rb1;
    const float* xin = x + (size_t)b * CHN * NPIX;

    const int pxq = t % 80;            // 4-px group
    const int ocq = t / 80;            // 0..3
    const int r   = pxq / 20;          // 0..3
    const int c   = (pxq % 20) * 4;    // 0..76
    const int oc0 = ocg * 16 + ocq * 4;
    const int gy0 = yt * 4;

    const int bl   = (blockIdx.z * 4 + blockIdx.y) * 20 + blockIdx.x;
    const int gtid = bl * 320 + t;
    const int nth  = 320 * 320;        // 102400
    const vf4 fz = {0.f, 0.f, 0.f, 0.f};

    float acc[4][4];
    #pragma unroll
    for (int j = 0; j < 4; j++)
        #pragma unroll
        for (int o = 0; o < 4; o++) acc[j][o] = b1[oc0 + o];

    for (int cc = 0; cc < 4; cc++) {
        const int icc = cc * 16;
        __syncthreads();
        for (int j = t; j < 1920; j += 320) {
            int ic_l = j / 120; int rem = j % 120;
            int row_l = rem / 20; int c4 = (rem % 20) * 4;
            int gy = gy0 - 1 + row_l;
            float4 v = make_float4(0.f, 0.f, 0.f, 0.f);
            if ((unsigned)gy < 80u)
                v = *(const float4*)(xin + (size_t)(icc + ic_l) * NPIX + gy * NXX + c4);
            *(float4*)&lx[ic_l][row_l][c4] = v;
        }
        for (int j = t; j < 2304; j += 320) {
            int oc_l = j % 16; int k = j / 16;
            int ic_l = k / 9, tap = k % 9;
            lw[k][oc_l] = w1[((size_t)(ocg * 16 + oc_l) * CHN + icc + ic_l) * 9 + tap];
        }
        __syncthreads();
        // zero-fill slice, phase cc
        {
            int i0 = cc * 24, i1 = cc * 24 + 24;
            for (int i = i0; i < i1; i++) {
                long q = QHM1 + (long)gtid + (long)i * nth;
                if (q < QWR1) __builtin_nontemporal_store(fz, outq + q);
            }
        }
        for (int ic = 0; ic < 16; ic++) {
            float xw[3][6];
            #pragma unroll
            for (int ky = 0; ky < 3; ky++) {
                const float* row = &lx[ic][r + ky][0];
                xw[ky][0] = (c > 0) ? row[c - 1] : 0.f;
                float4 m = *(const float4*)&row[c];
                xw[ky][1] = m.x; xw[ky][2] = m.y;
                xw[ky][3] = m.z; xw[ky][4] = m.w;
                xw[ky][5] = (c < 76) ? row[c + 4] : 0.f;
            }
            #pragma unroll
            for (int ky = 0; ky < 3; ky++)
            #pragma unroll
            for (int kx = 0; kx < 3; kx++) {
                const float* wv = &lw[ic * 9 + ky * 3 + kx][ocq * 4];
                float w0 = wv[0], w1v = wv[1], w2 = wv[2], w3 = wv[3];
                #pragma unroll
                for (int j = 0; j < 4; j++) {
                    float xv = xw[ky][j + kx];
                    acc[j][0] += xv * w0; acc[j][1] += xv * w1v;
                    acc[j][2] += xv * w2; acc[j][3] += xv * w3;
                }
            }
        }
    }
    size_t pix = (size_t)(gy0 + r) * NXX + c;
    #pragma unroll
    for (int o = 0; o < 4; o++) {
        float4 v;
        v.x = fmaxf(acc[0][o], 0.f); v.y = fmaxf(acc[1][o], 0.f);
        v.z = fmaxf(acc[2][o], 0.f); v.w = fmaxf(acc[3][o], 0.f);
        *(float4*)(c1 + ((size_t)img * CHN + oc0 + o) * NPIX + pix) = v;
    }
}

// ============ K2a: hm 1x1 conv -> RAW LOGIT, FP64 ============
// grid (25, 20, 2), 256 thr, 4 oc/thread
__global__ void conv2_hm_kernel(const double* __restrict__ c1,
                                const float* __restrict__ w2,
                                const float* __restrict__ b2,
                                double* __restrict__ hm_z,
                                vf4* __restrict__ outq)
{
    int p   = blockIdx.x * 256 + threadIdx.x;
    int oc0 = blockIdx.y * 4;
    int b   = blockIdx.z;

    // zero-fill slice (stores drain under the fp64 dot products)
    {
        const int bl   = (blockIdx.z * 20 + blockIdx.y) * 25 + blockIdx.x;
        const int gtid = bl * 256 + threadIdx.x;
        const vf4 fz = {0.f, 0.f, 0.f, 0.f};
        for (int i = 0; i < 9; i++) {
            long q = QFL1 + (long)gtid + (long)i * 256000;
            if (q < QC21) __builtin_nontemporal_store(fz, outq + q);
        }
    }

    const double* in = c1 + (size_t)b * CHN * NPIX;
    double acc[4];
    #pragma unroll
    for (int o = 0; o < 4; o++) acc[o] = (double)b2[oc0 + o];

    for (int ic = 0; ic < CHN; ic++) {
        double xv = in[(size_t)ic * NPIX + p];
        #pragma unroll
        for (int o = 0; o < 4; o++)
            acc[o] += xv * (double)w2[(size_t)(oc0 + o) * CHN + ic];
    }
    #pragma unroll
    for (int o = 0; o < 4; o++)
        hm_z[((size_t)b * NCLS + oc0 + o) * NPIX + p] = acc[o];
}

// ============ K2b: wh/reg 1x1 conv + relu, FP32 ============
__global__ void conv2_wr_kernel(const float* __restrict__ c1,
                                const float* __restrict__ wh_w2, const float* __restrict__ wh_b2,
                                const float* __restrict__ rg_w2, const float* __restrict__ rg_b2,
                                float* __restrict__ wh, float* __restrict__ rg)
{
    int p  = blockIdx.x * 256 + threadIdx.x;
    int hc = blockIdx.y;
    int b  = blockIdx.z;
    int head = hc >> 1, ch = hc & 1;

    const float* in = c1 + ((size_t)(head * 2 + b) * CHN) * NPIX;
    const float* w  = (head == 0) ? wh_w2 + (size_t)ch * CHN : rg_w2 + (size_t)ch * CHN;
    float bias      = (head == 0) ? wh_b2[ch] : rg_b2[ch];

    float acc = bias;
    for (int ic = 0; ic < CHN; ic++) acc += in[(size_t)ic * NPIX + p] * w[ic];
    acc = fmaxf(acc, 0.f);
    float* o = (head == 0) ? wh : rg;
    o[((size_t)b * 2 + ch) * NPIX + p] = acc;
}

// ============ K3a: maxima flags on fp64 LOGITS (sigmoid is monotone) ============
__global__ void flags_kernel(const double* __restrict__ hm_z,
                             unsigned long long* __restrict__ ballots,
                             unsigned int* __restrict__ counts,
                             vf4* __restrict__ outq)
{
    int b = blockIdx.y;
    int k = blockIdx.x * 1024 + threadIdx.x;

    // zero-fill slice
    {
        const int gtid = (b * NBLK + blockIdx.x) * 1024 + threadIdx.x;
        const vf4 fz = {0.f, 0.f, 0.f, 0.f};
        for (int i = 0; i < 6; i++) {
            long q = QWR1 + (long)gtid + (long)i * 1024000;
            if (q < QFL1) __builtin_nontemporal_store(fz, outq + q);
        }
    }

    int c = k / NPIX;
    int p = k - c * NPIX;
    int y = p / NXX, xx = p - y * NXX;

    const double* h = hm_z + ((size_t)b * NCLS + c) * NPIX;
    double s = h[p];
    double m = s;
    #pragma unroll
    for (int dy = -1; dy <= 1; dy++) {
        int yy = y + dy;
        if ((unsigned)yy >= (unsigned)NYY) continue;
        const double* hr = h + yy * NXX;
        #pragma unroll
        for (int dx = -1; dx <= 1; dx++) {
            int xn = xx + dx;
            if ((unsigned)xn >= (unsigned)NXX) continue;
            double v = hr[xn];
            m = v > m ? v : m;
        }
    }
    bool flag = (s == m);
    unsigned long long ball = __ballot(flag);
    int lane = threadIdx.x & 63;
    int wave = threadIdx.x >> 6;

    __shared__ unsigned int wcnt[16];
    if (lane == 0) {
        ballots[(size_t)b * 8000 + blockIdx.x * 16 + wave] = ball;
        wcnt[wave] = __popcll(ball);
    }
    __syncthreads();
    if (threadIdx.x == 0) {
        unsigned int tot = 0;
        for (int i = 0; i < 16; i++) tot += wcnt[i];
        counts[b * NBLK + blockIdx.x] = tot;
    }
}

// ============ K3b: exclusive scan of 500 block counts per batch ============
__global__ void scan_kernel(const unsigned int* __restrict__ counts,
                            unsigned int* __restrict__ offs)
{
    int b = blockIdx.x;
    int t = threadIdx.x;
    unsigned int v = (t < NBLK) ? counts[b * NBLK + t] : 0u;
    unsigned int xi = v;
    #pragma unroll
    for (int d = 1; d < 64; d <<= 1) {
        unsigned int n = __shfl_up(xi, d, 64);
        if ((t & 63) >= d) xi += n;
    }
    __shared__ unsigned int wtot[8];
    __shared__ unsigned int wbase[8];
    if ((t & 63) == 63) wtot[t >> 6] = xi;
    __syncthreads();
    if (t == 0) {
        unsigned int a = 0;
        for (int i = 0; i < 8; i++) { wbase[i] = a; a += wtot[i]; }
    }
    __syncthreads();
    unsigned int excl = xi - v + wbase[t >> 6];
    if (t < NBLK) offs[b * NBLK + t] = excl;
}

// ============ K3c: scatter maxima rows (sigmoid only here) ============
__global__ void scatter_kernel(const unsigned long long* __restrict__ ballots,
                               const unsigned int* __restrict__ offs,
                               const double* __restrict__ hm_z,
                               const float* __restrict__ wh,
                               const float* __restrict__ rg,
                               const float* __restrict__ offsets,
                               float* __restrict__ out)
{
    int b = blockIdx.y;
    int k = blockIdx.x * 1024 + threadIdx.x;
    int lane = threadIdx.x & 63;
    int wave = threadIdx.x >> 6;

    unsigned long long ball = ballots[(size_t)b * 8000 + blockIdx.x * 16 + wave];

    __shared__ unsigned int wc[16];
    __shared__ unsigned int wb[16];
    if (lane == 0) wc[wave] = __popcll(ball);
    __syncthreads();
    if (threadIdx.x == 0) {
        unsigned int a = 0;
        for (int i = 0; i < 16; i++) { wb[i] = a; a += wc[i]; }
    }
    __syncthreads();

    bool flag = (ball >> lane) & 1ull;
    if (!flag) return;

    unsigned int rank = offs[b * NBLK + blockIdx.x] + wb[wave]
                      + (unsigned int)__popcll(ball & ((1ull << lane) - 1ull));

    int c = k / NPIX;
    int p = k - c * NPIX;
    int y = p / NXX, xx = p - y * NXX;

    float offx = offsets[b * 3 + 1];
    float offy = offsets[b * 3 + 2];
    float r0 = rg[((size_t)b * 2 + 0) * NPIX + p];
    float r1 = rg[((size_t)b * 2 + 1) * NPIX + p];
    float w0 = wh[((size_t)b * 2 + 0) * NPIX + p];
    float w1 = wh[((size_t)b * 2 + 1) * NPIX + p];
    double z = hm_z[((size_t)b * NCLS + c) * NPIX + p];
    float s  = (float)(1.0 / (1.0 + exp(-z)));

    float cx = ((float)xx + 2.f * offx + r0) * 4.f;
    float cy = ((float)y  + 2.f * offy + r1) * 4.f;

    float* row = out + ((size_t)b * KTOT + rank) * NOUT;
    row[0] = cx;
    row[1] = cy;
    row[2] = w0 * 4.f;
    row[3] = w1 * 4.f;
    row[4] = s;
    row[5 + c] = 1.f;
}

extern "C" void kernel_launch(void* const* d_in, const int* in_sizes, int n_in,
                              void* d_out, int out_size, void* d_ws, size_t ws_size,
                              hipStream_t stream)
{
    const float* x       = (const float*)d_in[0];
    const float* offsets = (const float*)d_in[1];
    const float* hm_w1   = (const float*)d_in[2];
    const float* hm_b1   = (const float*)d_in[3];
    const float* hm_w2   = (const float*)d_in[4];
    const float* hm_b2   = (const float*)d_in[5];
    const float* wh_w1   = (const float*)d_in[6];
    const float* wh_b1   = (const float*)d_in[7];
    const float* wh_w2   = (const float*)d_in[8];
    const float* wh_b2   = (const float*)d_in[9];
    const float* reg_w1  = (const float*)d_in[10];
    const float* reg_b1  = (const float*)d_in[11];
    const float* reg_w2  = (const float*)d_in[12];
    const float* reg_b2  = (const float*)d_in[13];

    float* out = (float*)d_out;
    vf4* outq  = (vf4*)d_out;

    // workspace layout
    char* wp = (char*)d_ws;
    double* c1hm = (double*)wp;                 wp += (size_t)NBATCH * CHN * NPIX * 8;
    double* hm_z = (double*)wp;                 wp += (size_t)NBATCH * NCLS * NPIX * 8;
    float*  c1wr = (float*)wp;                  wp += (size_t)2 * NBATCH * CHN * NPIX * 4;
    float*  wh   = (float*)wp;                  wp += (size_t)NBATCH * 2 * NPIX * 4;
    float*  rg   = (float*)wp;                  wp += (size_t)NBATCH * 2 * NPIX * 4;
    unsigned long long* ballots = (unsigned long long*)wp; wp += (size_t)NBATCH * 8000 * 8;
    unsigned int* counts = (unsigned int*)wp;   wp += (size_t)NBATCH * NBLK * 4;
    unsigned int* offs   = (unsigned int*)wp;

    conv1_hm_kernel<<<dim3(40, 4, 2), 320, 0, stream>>>(x, hm_w1, hm_b1, c1hm, outq);

    conv1_wr_kernel<<<dim3(20, 4, 4), 320, 0, stream>>>(
        x, wh_w1, wh_b1, reg_w1, reg_b1, c1wr, outq);

    conv2_hm_kernel<<<dim3(25, 20, 2), 256, 0, stream>>>(c1hm, hm_w2, hm_b2, hm_z, outq);

    conv2_wr_kernel<<<dim3(25, 4, 2), 256, 0, stream>>>(
        c1wr, wh_w2, wh_b2, reg_w2, reg_b2, wh, rg);

    flags_kernel<<<dim3(NBLK, 2), 1024, 0, stream>>>(hm_z, ballots, counts, outq);

    scan_kernel<<<2, 512, 0, stream>>>(counts, offs);

    scatter_kernel<<<dim3(NBLK, 2), 1024, 0, stream>>>(
        ballots, offs, hm_z, wh, rg, offsets, out);
}